// Round 5
// baseline (344.511 us; speedup 1.0000x reference)
//
#include <hip/hip_runtime.h>
#include <math.h>

#define NB 16
#define NC 256
#define NH 56
#define NW 56
#define NHW 3136
#define NHID 65
#define NK 4
#define NOC 256
#define WN 589824            // 256*256*9
#define OUT0 12845056        // 16*256*56*56

// ws header (float indices)
#define WS_POOLED 0          // [4096] (fallback path only)
#define WS_KB     4096       // [16] ints
#define WS_MAX    4112       // [1] (fallback path only)
#define WS_MAXP   4128       // [256] non-atomic maxtanh partials (mfma path)
#define WS_WQF    8192       // fallback fp32 banks [4][WN]
// byte offsets (MFMA path)
#define WQB_OFF   32768ul    // bf16 packed A-frags [4][8 ot][8 cs][18 f][64 lane][8] = 4,718,592 B
#define XP_OFF    4751360ul  // bf16 [16][58 row][58 col][256 ch] = 27,574,272 B
#define WS_NEED   32325632ul
// pooling partials in OUT scratch: [b][c][56 y] fp32 = 917,504 B (conv overwrites later)

typedef unsigned int u32;
typedef unsigned short u16;
typedef unsigned long long u64;
typedef __attribute__((ext_vector_type(8))) short s8v;
typedef __attribute__((ext_vector_type(16))) float f16v;

__device__ __forceinline__ u16 f2bf(float f) {
    union { float f; u32 u; } v; v.f = f;
    u32 u = v.u;
    return (u16)((u + 0x7fffu + ((u >> 16) & 1u)) >> 16);
}

__device__ __forceinline__ void gload_lds16(const void* g, void* l) {
    __builtin_amdgcn_global_load_lds((const __attribute__((address_space(1))) u32*)g,
                                     (__attribute__((address_space(3))) u32*)l, 16, 0, 0);
}

// ---------------- MFMA path: 3 kernels ----------------

#define LBT_P 260            // u16 pitch: even dwords->4-way max, u64-aligned rows

// k_prep: grid 480 x 256.
//  blocks 0..223: (b,yg) transpose 4 rows -> xp bf16 + per-row channel sums -> scratch
//  blocks 224..479: maxtanh partials -> ws[WS_MAXP + j]
__global__ __launch_bounds__(256) void k_prep(const float* __restrict__ x,
                                              const float* __restrict__ w,
                                              float* __restrict__ ws,
                                              float* __restrict__ scratch) {
    const int tid = threadIdx.x;
    if (blockIdx.x >= 224) {                     // maxtanh partial
        int j = blockIdx.x - 224;
        float m = 0.f;
        for (int i = j * 256 + tid; i < WN; i += 65536)
            m = fmaxf(m, fabsf(tanhf(w[i])));
        for (int off = 32; off > 0; off >>= 1) m = fmaxf(m, __shfl_down(m, off, 64));
        __shared__ float part[4];
        int lane = tid & 63, wv = tid >> 6;
        if (lane == 0) part[wv] = m;
        __syncthreads();
        if (tid == 0)
            ws[WS_MAXP + j] = fmaxf(fmaxf(part[0], part[1]), fmaxf(part[2], part[3]));
        return;
    }
    const int b = blockIdx.x / 14, yg = blockIdx.x % 14;
    const int lane = tid & 63, wv = tid >> 6;
    __shared__ u16 Lbt[56 * LBT_P];              // [w][c], lane->w stores: <=4-way
    u16* xp = (u16*)((char*)ws + XP_OFF);

    for (int ry = 0; ry < 4; ++ry) {
        const int y = yg * 4 + ry;
        if (ry) __syncthreads();                 // pack of previous row done
        #pragma unroll 4
        for (int cg = 0; cg < 64; ++cg) {
            int c = cg * 4 + wv;
            float v = 0.f;
            if (lane < 56)
                v = x[((size_t)(b * 256 + c)) * NHW + (size_t)y * 56 + lane];
            if (lane < 56) Lbt[lane * LBT_P + c] = f2bf(v);
            float s = v;
            for (int off = 32; off > 0; off >>= 1) s += __shfl_down(s, off, 64);
            if (lane == 0)
                scratch[((size_t)(b * 256 + c)) * 56 + y] = s;
        }
        __syncthreads();
        u64* rowp = (u64*)xp + (size_t)(b * 58 + y + 1) * (58 * 64);
        for (int idx = tid; idx < 58 * 64; idx += 256) {
            int col = idx >> 6, cp = idx & 63;
            u64 v = 0ull;
            if (col >= 1 && col <= 56)
                v = *(const u64*)(Lbt + (col - 1) * LBT_P + cp * 4);
            rowp[idx] = v;
        }
    }
    if (yg == 0 || yg == 13) {                   // zero border rows 0 / 57
        int row = (yg == 0) ? 0 : 57;
        u64* rowp = (u64*)xp + (size_t)(b * 58 + row) * (58 * 64);
        for (int idx = tid; idx < 58 * 64; idx += 256) rowp[idx] = 0ull;
    }
}

// k_mid: grid 144 x 256. blocks 0..15: fc+argmax; 16..143: quant+pack.
__global__ __launch_bounds__(256) void k_mid(const float* __restrict__ w_fc1,
                                             const float* __restrict__ w_fc2,
                                             const float* __restrict__ b_fc2,
                                             const float* __restrict__ w,
                                             float* __restrict__ ws,
                                             const float* __restrict__ scratch,
                                             float* __restrict__ out_raw) {
    const int tid = threadIdx.x;
    if (blockIdx.x < 16) {                       // ---- fc ----
        const int b = blockIdx.x;
        __shared__ float pl[NC];
        __shared__ float hs[NHID];
        __shared__ float raws[NK];
        float p = 0.f;
        for (int y = 0; y < 56; ++y)
            p += scratch[((size_t)(b * 256 + tid)) * 56 + y];
        pl[tid] = p * (1.0f / NHW);
        __syncthreads();
        if (tid < NHID) {
            float s = 0.f;
            for (int c = 0; c < NC; ++c) s = fmaf(pl[c], w_fc1[tid * NC + c], s);
            hs[tid] = fmaxf(s, 0.f);
        }
        __syncthreads();
        if (tid < NK) {
            float s = b_fc2[tid];
            for (int j = 0; j < NHID; ++j) s = fmaf(hs[j], w_fc2[tid * NHID + j], s);
            raws[tid] = s;
            out_raw[b * NK + tid] = s;
        }
        __syncthreads();
        if (tid == 0) {
            int best = 0;
            for (int k = 1; k < NK; ++k) if (raws[k] > raws[best]) best = k;
            ((int*)(ws + WS_KB))[b] = best;
        }
        return;
    }
    // ---- quant + pack ----
    __shared__ float mred[4];
    float mv = ws[WS_MAXP + tid];
    for (int off = 32; off > 0; off >>= 1) mv = fmaxf(mv, __shfl_down(mv, off, 64));
    if ((tid & 63) == 0) mred[tid >> 6] = mv;
    __syncthreads();
    const float maxt = fmaxf(fmaxf(mred[0], mred[1]), fmaxf(mred[2], mred[3]));

    u16* wqp = (u16*)((char*)ws + WQB_OFF);
    int idx = (blockIdx.x - 16) * 256 + tid;     // 128 blocks: 256 o x 128 c2
    int o = idx >> 7, c2 = idx & 127;
    int ch0 = c2 * 2;
    int cs = ch0 >> 5, cc = ch0 & 31;
    int ks2 = cc >> 4, hf = (cc >> 3) & 1, j = cc & 7;
    int n = o & 31, ot = o >> 5;
    const float* wp = w + ((size_t)o * 256 + ch0) * 9;
    float t0[9], t1[9];
    #pragma unroll
    for (int t = 0; t < 9; ++t) t0[t] = tanhf(wp[t]);
    #pragma unroll
    for (int t = 0; t < 9; ++t) t1[t] = tanhf(wp[9 + t]);
    #pragma unroll
    for (int bank = 0; bank < 4; ++bank) {
        float a = (float)(4 << bank);
        #pragma unroll
        for (int tap = 0; tap < 9; ++tap) {
            float xq0 = (t0[tap] / maxt + 1.f) * 0.5f;
            float xq1 = (t1[tap] / maxt + 1.f) * 0.5f;
            float q0 = fminf(floorf(a * xq0), a - 1.f) / a * 2.f - 1.f;
            float q1 = fminf(floorf(a * xq1), a - 1.f) / a * 2.f - 1.f;
            u32 pk = (u32)f2bf(q0) | ((u32)f2bf(q1) << 16);
            size_t off16 = ((((size_t)((bank * 8 + ot) * 8 + cs)) * 18 + tap * 2 + ks2) * 64
                            + hf * 32 + n) * 8 + j;
            *(u32*)(wqp + off16) = pk;
        }
    }
}

// Implicit-GEMM conv, mfma_f32_32x32x16_bf16.
// grid (4 o-quarters, 7 strips of 8 rows, 16 b) = 448; block 256 = 4 waves.
// Block: M=64 x N=448. Each wave: BOTH o-tiles (B-frag reused for 2 MFMAs -> LDS/2),
// waves split N as 4/4/3/3 tiles. Double-buffered LDS, 2 blocks/CU.
__global__ __launch_bounds__(256, 2) void k_conv_mfma(const float* __restrict__ bias,
                                                      const float* __restrict__ ws_f,
                                                      float* __restrict__ out) {
    const int oq = blockIdx.x;                   // o base = oq*64
    const int r0 = blockIdx.y * 8;
    const int b  = blockIdx.z;
    const int tid = threadIdx.x;
    const int wv = tid >> 6, lane = tid & 63;
    const int n = lane & 31, hf = lane >> 5;
    const int noff  = (wv < 2) ? wv * 4 : 8 + (wv - 2) * 3;
    const int ntile = (wv < 2) ? 4 : 3;
    const int kb = ((const int*)(ws_f + WS_KB))[b];
    const u16* wqp = (const u16*)((const char*)ws_f + WQB_OFF);
    const u16* xp  = (const u16*)((const char*)ws_f + XP_OFF);

    __shared__ __align__(16) u16 Xl[2][20480];   // 2 x [10 row][4 oct][64 col]x16B = 2x40 KB

    int bofs[4];
    #pragma unroll
    for (int t = 0; t < 4; ++t) {
        int p = (noff + t) * 32 + n;
        if (t >= ntile) p = n;                   // harmless dummy
        int pr = p / 56, pc = p - pr * 56;
        bofs[t] = pr * 4096 + hf * 1024 + pc * 16;
    }
    const int colc = (lane < 58) ? lane : 57;
    const u16* xsrc = xp + (((size_t)(b * 58 + r0)) * 58 + colc) * 256;
    const u16* ab0 = wqp + (size_t)((kb * 8 + oq * 2 + 0) * 8) * (18 * 64 * 8);
    const u16* ab1 = wqp + (size_t)((kb * 8 + oq * 2 + 1) * 8) * (18 * 64 * 8);

    f16v acc0[4], acc1[4];
    #pragma unroll
    for (int t = 0; t < 4; ++t) { acc0[t] = (f16v)0.f; acc1[t] = (f16v)0.f; }

    // prologue stage cs=0 -> buf 0: 40 segs of 1KB, 10 per wave
    #pragma unroll
    for (int i = 0; i < 10; ++i) {
        int seg = wv * 10 + i;
        gload_lds16(xsrc + (size_t)(seg >> 2) * (58 * 256) + (seg & 3) * 8,
                    (void*)(&Xl[0][seg * 512]));
    }
    __syncthreads();

    #pragma unroll 1
    for (int cs = 0; cs < 8; ++cs) {
        int pb = cs & 1;
        if (cs < 7) {
            int c0n = (cs + 1) * 32;
            #pragma unroll
            for (int i = 0; i < 10; ++i) {
                int seg = wv * 10 + i;
                gload_lds16(xsrc + (size_t)(seg >> 2) * (58 * 256) + (seg & 3) * 8 + c0n,
                            (void*)(&Xl[pb ^ 1][seg * 512]));
            }
        }
        const u16* ap0 = ab0 + (size_t)cs * (18 * 64 * 8);
        const u16* ap1 = ab1 + (size_t)cs * (18 * 64 * 8);
        const char* XB = (const char*)&Xl[pb][0];
        #pragma unroll
        for (int r = 0; r < 3; ++r) {
            s8v a0[6], a1[6];                    // f = r*6 + s*2 + ks
            #pragma unroll
            for (int j = 0; j < 6; ++j) {
                a0[j] = *(const s8v*)(ap0 + (size_t)((r * 6 + j) * 64 + lane) * 8);
                a1[j] = *(const s8v*)(ap1 + (size_t)((r * 6 + j) * 64 + lane) * 8);
            }
            #pragma unroll
            for (int s = 0; s < 3; ++s)
                #pragma unroll
                for (int ks = 0; ks < 2; ++ks) {
                    const int coff = r * 4096 + ks * 2048 + s * 16;
                    #pragma unroll
                    for (int t = 0; t < 4; ++t)
                        if (t < ntile) {
                            s8v bf = *(const s8v*)(XB + bofs[t] + coff);
                            acc0[t] = __builtin_amdgcn_mfma_f32_32x32x16_bf16(a0[s * 2 + ks], bf, acc0[t], 0, 0, 0);
                            acc1[t] = __builtin_amdgcn_mfma_f32_32x32x16_bf16(a1[s * 2 + ks], bf, acc1[t], 0, 0, 0);
                        }
                }
        }
        __syncthreads();
    }

    #pragma unroll
    for (int t = 0; t < 4; ++t)
        if (t < ntile) {
            int p = (noff + t) * 32 + n, pr = p / 56, pc = p - pr * 56;
            float* op = out + (size_t)b * 256 * NHW + (size_t)(r0 + pr) * 56 + pc;
            #pragma unroll
            for (int reg = 0; reg < 16; ++reg) {
                int m = (reg & 3) + 8 * (reg >> 2) + 4 * hf;
                int o0 = oq * 64 + m;
                op[(size_t)o0 * NHW] = acc0[t][reg] + bias[kb * NOC + o0];
                op[(size_t)(o0 + 32) * NHW] = acc1[t][reg] + bias[kb * NOC + o0 + 32];
            }
        }
}

// ---------------- fallback fp32 path ----------------

__global__ __launch_bounds__(256) void k_pool(const float* __restrict__ x,
                                              float* __restrict__ ws) {
    int plane = blockIdx.x;
    const float* p = x + (size_t)plane * NHW;
    float s = 0.f;
    for (int i = threadIdx.x; i < NHW; i += 256) s += p[i];
    for (int off = 32; off > 0; off >>= 1) s += __shfl_down(s, off, 64);
    __shared__ float part[4];
    int lane = threadIdx.x & 63, wv = threadIdx.x >> 6;
    if (lane == 0) part[wv] = s;
    __syncthreads();
    if (threadIdx.x == 0)
        ws[WS_POOLED + plane] = part[0] + part[1] + part[2] + part[3];
}

__global__ __launch_bounds__(256) void k_fc(const float* __restrict__ w_fc1,
                                            const float* __restrict__ w_fc2,
                                            const float* __restrict__ b_fc2,
                                            float* __restrict__ ws,
                                            float* __restrict__ out_raw) {
    __shared__ float pl[NB * NC];
    __shared__ float hs[NB][NHID];
    __shared__ float raws[NB][NK];
    for (int i = threadIdx.x; i < NB * NC; i += 256)
        pl[i] = ws[WS_POOLED + i] * (1.0f / NHW);
    __syncthreads();
    for (int idx = threadIdx.x; idx < NB * NHID; idx += 256) {
        int b = idx / NHID, j = idx % NHID;
        float s = 0.f;
        for (int c = 0; c < NC; ++c) s = fmaf(pl[b * NC + c], w_fc1[j * NC + c], s);
        hs[b][j] = fmaxf(s, 0.f);
    }
    __syncthreads();
    if (threadIdx.x < NB * NK) {
        int b = threadIdx.x / NK, k = threadIdx.x % NK;
        float s = b_fc2[k];
        for (int j = 0; j < NHID; ++j) s = fmaf(hs[b][j], w_fc2[k * NHID + j], s);
        raws[b][k] = s;
        out_raw[b * NK + k] = s;
    }
    __syncthreads();
    if (threadIdx.x < NB) {
        int best = 0;
        for (int k = 1; k < NK; ++k)
            if (raws[threadIdx.x][k] > raws[threadIdx.x][best]) best = k;
        ((int*)(ws + WS_KB))[threadIdx.x] = best;
    }
}

__global__ __launch_bounds__(256) void k_maxtanh(const float* __restrict__ w,
                                                 float* __restrict__ ws) {
    float m = 0.f;
    for (int i = blockIdx.x * 256 + threadIdx.x; i < WN; i += gridDim.x * 256)
        m = fmaxf(m, fabsf(tanhf(w[i])));
    for (int off = 32; off > 0; off >>= 1) m = fmaxf(m, __shfl_down(m, off, 64));
    __shared__ float part[4];
    int lane = threadIdx.x & 63, wv = threadIdx.x >> 6;
    if (lane == 0) part[wv] = m;
    __syncthreads();
    if (threadIdx.x == 0) {
        float t = fmaxf(fmaxf(part[0], part[1]), fmaxf(part[2], part[3]));
        atomicMax((unsigned int*)ws + WS_MAX, __float_as_uint(t));
    }
}

__global__ __launch_bounds__(256) void k_quant(const float* __restrict__ w,
                                               float* __restrict__ ws) {
    float maxt = __uint_as_float(((const unsigned int*)ws)[WS_MAX]);
    float* wqf = ws + WS_WQF;
    for (int i = blockIdx.x * 256 + threadIdx.x; i < WN; i += gridDim.x * 256) {
        float t = tanhf(w[i]);
        float xq = (t / maxt + 1.0f) * 0.5f;
        #pragma unroll
        for (int k = 0; k < NK; ++k) {
            float a = (float)(4 << k);
            float q = fminf(floorf(a * xq), a - 1.0f) / a;
            wqf[(size_t)k * WN + i] = q * 2.0f - 1.0f;
        }
    }
}

__global__ __launch_bounds__(256) void k_conv(const float* __restrict__ x,
                                              const float* __restrict__ bias,
                                              const float* __restrict__ ws,
                                              float* __restrict__ out) {
    const int o_base = blockIdx.x * 16;
    const int row_base = blockIdx.y * 7;
    const int b = blockIdx.z;
    const int tid = threadIdx.x;
    const int w = tid & 63;
    const int og = tid >> 6;
    const int wc = (w < 56) ? w : 55;
    const int kb = ((const int*)(ws + WS_KB))[b];
    const float* wqf = ws + WS_WQF + (size_t)kb * WN;

    __shared__ float Xl[8][9][58];
    __shared__ float Wl[16][72];

    float acc[4][7];
    #pragma unroll
    for (int i = 0; i < 4; ++i)
        #pragma unroll
        for (int j = 0; j < 7; ++j) acc[i][j] = 0.f;

    for (int c0 = 0; c0 < NC; c0 += 8) {
        for (int idx = tid; idx < 1152; idx += 256) {
            int o = idx / 72, rem = idx - o * 72;
            Wl[o][rem] = wqf[(size_t)(o_base + o) * 2304 + c0 * 9 + rem];
        }
        for (int idx = tid; idx < 4176; idx += 256) {
            int c = idx / 522, rem = idx - c * 522;
            int ly = rem / 58, lx = rem - ly * 58;
            int gy = row_base - 1 + ly, gx = lx - 1;
            float v = 0.f;
            if (gy >= 0 && gy < NH && (unsigned)gx < (unsigned)NW)
                v = x[(((size_t)b * NC + c0 + c) * NH + gy) * NW + gx];
            Xl[c][ly][lx] = v;
        }
        __syncthreads();
        #pragma unroll 1
        for (int c = 0; c < 8; ++c) {
            float xv[9][3];
            #pragma unroll
            for (int ly = 0; ly < 9; ++ly)
                #pragma unroll
                for (int s = 0; s < 3; ++s)
                    xv[ly][s] = Xl[c][ly][wc + s];
            float wvv[4][9];
            #pragma unroll
            for (int i = 0; i < 4; ++i)
                #pragma unroll
                for (int t = 0; t < 9; ++t)
                    wvv[i][t] = Wl[og * 4 + i][c * 9 + t];
            #pragma unroll
            for (int i = 0; i < 4; ++i)
                #pragma unroll
                for (int j = 0; j < 7; ++j)
                    #pragma unroll
                    for (int r = 0; r < 3; ++r)
                        #pragma unroll
                        for (int s = 0; s < 3; ++s)
                            acc[i][j] = fmaf(wvv[i][r * 3 + s], xv[j + r][s], acc[i][j]);
        }
        __syncthreads();
    }

    if (w < 56) {
        #pragma unroll
        for (int i = 0; i < 4; ++i) {
            int o = o_base + og * 4 + i;
            float bb = bias[kb * NOC + o];
            #pragma unroll
            for (int j = 0; j < 7; ++j)
                out[(((size_t)b * NOC + o) * NH + (row_base + j)) * NW + w] = acc[i][j] + bb;
        }
    }
}

extern "C" void kernel_launch(void* const* d_in, const int* in_sizes, int n_in,
                              void* d_out, int out_size, void* d_ws, size_t ws_size,
                              hipStream_t stream) {
    const float* x      = (const float*)d_in[0];
    const float* w_fc1  = (const float*)d_in[1];
    const float* w_fc2  = (const float*)d_in[2];
    const float* b_fc2  = (const float*)d_in[3];
    const float* weight = (const float*)d_in[4];
    const float* bias   = (const float*)d_in[5];
    float* out = (float*)d_out;
    float* ws  = (float*)d_ws;

    if (ws_size >= WS_NEED) {
        hipLaunchKernelGGL(k_prep, dim3(480), dim3(256), 0, stream, x, weight, ws, out);
        hipLaunchKernelGGL(k_mid, dim3(144), dim3(256), 0, stream,
                           w_fc1, w_fc2, b_fc2, weight, ws, out, out + OUT0);
        hipLaunchKernelGGL(k_conv_mfma, dim3(4, 7, 16), dim3(256), 0, stream, bias, ws, out);
    } else {
        hipLaunchKernelGGL(k_pool, dim3(NB * NC), dim3(256), 0, stream, x, ws);
        hipLaunchKernelGGL(k_fc, dim3(1), dim3(256), 0, stream,
                           w_fc1, w_fc2, b_fc2, ws, out + OUT0);
        hipLaunchKernelGGL(k_maxtanh, dim3(256), dim3(256), 0, stream, weight, ws);
        hipLaunchKernelGGL(k_quant, dim3(512), dim3(256), 0, stream, weight, ws);
        hipLaunchKernelGGL(k_conv, dim3(16, 8, NB), dim3(256), 0, stream, x, bias, ws, out);
    }
}

// Round 6
// 201.925 us; speedup vs baseline: 1.7061x; 1.7061x over previous
//
#include <hip/hip_runtime.h>
#include <math.h>

#define NB 16
#define NC 256
#define NH 56
#define NW 56
#define NHW 3136
#define NHID 65
#define NK 4
#define NOC 256
#define WN 589824            // 256*256*9
#define OUT0 12845056        // 16*256*56*56

// ws header (float indices)
#define WS_POOLED 0          // [4096] (fallback path only)
#define WS_KB     4096       // [16] ints
#define WS_MAX    4112       // [1] (fallback path only)
#define WS_MAXP   4128       // [256] non-atomic maxtanh partials (mfma path)
#define WS_WQF    8192       // fallback fp32 banks [4][WN]
// byte offsets (MFMA path)
#define WQB_OFF   32768ul    // bf16 packed A-frags [4][8 ot][8 cs][18 f][64 lane][8] = 4,718,592 B
#define XP_OFF    4751360ul  // bf16 [16][58 row][58 col][256 ch] = 27,574,272 B
#define WS_NEED   32325632ul
// pooling partials in OUT scratch: [b][y][c] fp32 = 917,504 B (conv overwrites later)

typedef unsigned int u32;
typedef unsigned short u16;
typedef unsigned long long u64;
typedef __attribute__((ext_vector_type(8))) short s8v;
typedef __attribute__((ext_vector_type(16))) float f16v;

__device__ __forceinline__ u16 f2bf(float f) {
    union { float f; u32 u; } v; v.f = f;
    u32 u = v.u;
    return (u16)((u + 0x7fffu + ((u >> 16) & 1u)) >> 16);
}

__device__ __forceinline__ void gload_lds16(const void* g, void* l) {
    __builtin_amdgcn_global_load_lds((const __attribute__((address_space(1))) u32*)g,
                                     (__attribute__((address_space(3))) u32*)l, 16, 0, 0);
}

// ---------------- MFMA path: 3 kernels ----------------

// k_prep: grid 1152 x 256.
//  blocks 0..895  : (b*56+y) transpose ONE row -> xp bf16 + per-row channel sums -> scratch[b][y][c]
//  blocks 896..1151: maxtanh partials -> ws[WS_MAXP + j]
// One block per row: 16 independent float4 loads/thread (MLP), single barrier, coalesced pack.
__global__ __launch_bounds__(256) void k_prep(const float* __restrict__ x,
                                              const float* __restrict__ w,
                                              float* __restrict__ ws,
                                              float* __restrict__ scratch) {
    const int tid = threadIdx.x;
    if (blockIdx.x >= 896) {                     // maxtanh partial
        int j = blockIdx.x - 896;
        float m = 0.f;
        for (int i = j * 256 + tid; i < WN; i += 65536)
            m = fmaxf(m, fabsf(tanhf(w[i])));
        for (int off = 32; off > 0; off >>= 1) m = fmaxf(m, __shfl_down(m, off, 64));
        __shared__ float part[4];
        int lane = tid & 63, wv = tid >> 6;
        if (lane == 0) part[wv] = m;
        __syncthreads();
        if (tid == 0)
            ws[WS_MAXP + j] = fmaxf(fmaxf(part[0], part[1]), fmaxf(part[2], part[3]));
        return;
    }
    const int by = blockIdx.x;                   // b*56 + y
    const int b = by / 56, y = by % 56;
    const int c16 = tid >> 4, q = tid & 15;      // 16 channels x 16 q-lanes
    __shared__ __align__(8) u16 Lbt[56 * 264];   // [w][c] pitch 264
    __shared__ float pl[256];
    u16* xp = (u16*)((char*)ws + XP_OFF);

    #pragma unroll
    for (int ci = 0; ci < 16; ++ci) {            // 16 independent iterations -> deep MLP
        int c = ci * 16 + c16;
        float4 v = make_float4(0.f, 0.f, 0.f, 0.f);
        if (q < 14) {
            v = *(const float4*)(x + ((size_t)(b * 256 + c)) * NHW + (size_t)y * 56 + q * 4);
            Lbt[(q * 4 + 0) * 264 + c] = f2bf(v.x);
            Lbt[(q * 4 + 1) * 264 + c] = f2bf(v.y);
            Lbt[(q * 4 + 2) * 264 + c] = f2bf(v.z);
            Lbt[(q * 4 + 3) * 264 + c] = f2bf(v.w);
        }
        float s = v.x + v.y + v.z + v.w;
        s += __shfl_down(s, 8, 16);
        s += __shfl_down(s, 4, 16);
        s += __shfl_down(s, 2, 16);
        s += __shfl_down(s, 1, 16);
        if (q == 0) pl[c] = s;
    }
    __syncthreads();
    scratch[(size_t)by * 256 + tid] = pl[tid];   // coalesced 1KB store
    u64* rowp = (u64*)xp + (size_t)(b * 58 + y + 1) * (58 * 64);
    for (int idx = tid; idx < 58 * 64; idx += 256) {
        int col = idx >> 6, cp = idx & 63;
        u64 v = 0ull;
        if (col >= 1 && col <= 56)
            v = *(const u64*)(Lbt + (col - 1) * 264 + cp * 4);
        rowp[idx] = v;
    }
    if (y == 0 || y == 55) {                     // zero border rows 0 / 57
        int row = (y == 0) ? 0 : 57;
        u64* brow = (u64*)xp + (size_t)(b * 58 + row) * (58 * 64);
        for (int idx = tid; idx < 58 * 64; idx += 256) brow[idx] = 0ull;
    }
}

// k_mid: grid 144 x 256. blocks 0..15: fc+argmax; 16..143: quant+pack.
__global__ __launch_bounds__(256) void k_mid(const float* __restrict__ w_fc1,
                                             const float* __restrict__ w_fc2,
                                             const float* __restrict__ b_fc2,
                                             const float* __restrict__ w,
                                             float* __restrict__ ws,
                                             const float* __restrict__ scratch,
                                             float* __restrict__ out_raw) {
    const int tid = threadIdx.x;
    if (blockIdx.x < 16) {                       // ---- fc ----
        const int b = blockIdx.x;
        __shared__ float pl[NC];
        __shared__ float hs[NHID];
        __shared__ float raws[NK];
        float p = 0.f;
        for (int y = 0; y < 56; ++y)             // coalesced across threads per y
            p += scratch[((size_t)(b * 56 + y)) * 256 + tid];
        pl[tid] = p * (1.0f / NHW);
        __syncthreads();
        if (tid < NHID) {
            float s = 0.f;
            for (int c = 0; c < NC; ++c) s = fmaf(pl[c], w_fc1[tid * NC + c], s);
            hs[tid] = fmaxf(s, 0.f);
        }
        __syncthreads();
        if (tid < NK) {
            float s = b_fc2[tid];
            for (int j = 0; j < NHID; ++j) s = fmaf(hs[j], w_fc2[tid * NHID + j], s);
            raws[tid] = s;
            out_raw[b * NK + tid] = s;
        }
        __syncthreads();
        if (tid == 0) {
            int best = 0;
            for (int k = 1; k < NK; ++k) if (raws[k] > raws[best]) best = k;
            ((int*)(ws + WS_KB))[b] = best;
        }
        return;
    }
    // ---- quant + pack ----
    __shared__ float mred[4];
    float mv = ws[WS_MAXP + tid];
    for (int off = 32; off > 0; off >>= 1) mv = fmaxf(mv, __shfl_down(mv, off, 64));
    if ((tid & 63) == 0) mred[tid >> 6] = mv;
    __syncthreads();
    const float maxt = fmaxf(fmaxf(mred[0], mred[1]), fmaxf(mred[2], mred[3]));

    u16* wqp = (u16*)((char*)ws + WQB_OFF);
    int idx = (blockIdx.x - 16) * 256 + tid;     // 128 blocks: 256 o x 128 c2
    int o = idx >> 7, c2 = idx & 127;
    int ch0 = c2 * 2;
    int cs = ch0 >> 5, cc = ch0 & 31;
    int ks2 = cc >> 4, hf = (cc >> 3) & 1, j = cc & 7;
    int n = o & 31, ot = o >> 5;
    const float* wp = w + ((size_t)o * 256 + ch0) * 9;
    float t0[9], t1[9];
    #pragma unroll
    for (int t = 0; t < 9; ++t) t0[t] = tanhf(wp[t]);
    #pragma unroll
    for (int t = 0; t < 9; ++t) t1[t] = tanhf(wp[9 + t]);
    #pragma unroll
    for (int bank = 0; bank < 4; ++bank) {
        float a = (float)(4 << bank);
        #pragma unroll
        for (int tap = 0; tap < 9; ++tap) {
            float xq0 = (t0[tap] / maxt + 1.f) * 0.5f;
            float xq1 = (t1[tap] / maxt + 1.f) * 0.5f;
            float q0 = fminf(floorf(a * xq0), a - 1.f) / a * 2.f - 1.f;
            float q1 = fminf(floorf(a * xq1), a - 1.f) / a * 2.f - 1.f;
            u32 pk = (u32)f2bf(q0) | ((u32)f2bf(q1) << 16);
            size_t off16 = ((((size_t)((bank * 8 + ot) * 8 + cs)) * 18 + tap * 2 + ks2) * 64
                            + hf * 32 + n) * 8 + j;
            *(u32*)(wqp + off16) = pk;
        }
    }
}

// Implicit-GEMM conv, mfma_f32_32x32x16_bf16.
// grid (4 o-quarters, 7 strips of 8 rows, 16 b) = 448; block 256 = 4 waves.
// Block: M=64 x N=448. Each wave: BOTH o-tiles (B-frag reused for 2 MFMAs -> LDS/2),
// waves split N as 4/4/3/3 tiles. Double-buffered LDS, 2 blocks/CU.
__global__ __launch_bounds__(256, 2) void k_conv_mfma(const float* __restrict__ bias,
                                                      const float* __restrict__ ws_f,
                                                      float* __restrict__ out) {
    const int oq = blockIdx.x;                   // o base = oq*64
    const int r0 = blockIdx.y * 8;
    const int b  = blockIdx.z;
    const int tid = threadIdx.x;
    const int wv = tid >> 6, lane = tid & 63;
    const int n = lane & 31, hf = lane >> 5;
    const int noff  = (wv < 2) ? wv * 4 : 8 + (wv - 2) * 3;
    const int ntile = (wv < 2) ? 4 : 3;
    const int kb = ((const int*)(ws_f + WS_KB))[b];
    const u16* wqp = (const u16*)((const char*)ws_f + WQB_OFF);
    const u16* xp  = (const u16*)((const char*)ws_f + XP_OFF);

    __shared__ __align__(16) u16 Xl[2][20480];   // 2 x [10 row][4 oct][64 col]x16B = 2x40 KB

    int bofs[4];
    #pragma unroll
    for (int t = 0; t < 4; ++t) {
        int p = (noff + t) * 32 + n;
        if (t >= ntile) p = n;                   // harmless dummy
        int pr = p / 56, pc = p - pr * 56;
        bofs[t] = pr * 4096 + hf * 1024 + pc * 16;
    }
    const int colc = (lane < 58) ? lane : 57;
    const u16* xsrc = xp + (((size_t)(b * 58 + r0)) * 58 + colc) * 256;
    const u16* ab0 = wqp + (size_t)((kb * 8 + oq * 2 + 0) * 8) * (18 * 64 * 8);
    const u16* ab1 = wqp + (size_t)((kb * 8 + oq * 2 + 1) * 8) * (18 * 64 * 8);

    f16v acc0[4], acc1[4];
    #pragma unroll
    for (int t = 0; t < 4; ++t) { acc0[t] = (f16v)0.f; acc1[t] = (f16v)0.f; }

    // prologue stage cs=0 -> buf 0: 40 segs of 1KB, 10 per wave
    #pragma unroll
    for (int i = 0; i < 10; ++i) {
        int seg = wv * 10 + i;
        gload_lds16(xsrc + (size_t)(seg >> 2) * (58 * 256) + (seg & 3) * 8,
                    (void*)(&Xl[0][seg * 512]));
    }
    __syncthreads();

    #pragma unroll 1
    for (int cs = 0; cs < 8; ++cs) {
        int pb = cs & 1;
        if (cs < 7) {
            int c0n = (cs + 1) * 32;
            #pragma unroll
            for (int i = 0; i < 10; ++i) {
                int seg = wv * 10 + i;
                gload_lds16(xsrc + (size_t)(seg >> 2) * (58 * 256) + (seg & 3) * 8 + c0n,
                            (void*)(&Xl[pb ^ 1][seg * 512]));
            }
        }
        const u16* ap0 = ab0 + (size_t)cs * (18 * 64 * 8);
        const u16* ap1 = ab1 + (size_t)cs * (18 * 64 * 8);
        const char* XB = (const char*)&Xl[pb][0];
        #pragma unroll
        for (int r = 0; r < 3; ++r) {
            s8v a0[6], a1[6];                    // f = r*6 + s*2 + ks
            #pragma unroll
            for (int j = 0; j < 6; ++j) {
                a0[j] = *(const s8v*)(ap0 + (size_t)((r * 6 + j) * 64 + lane) * 8);
                a1[j] = *(const s8v*)(ap1 + (size_t)((r * 6 + j) * 64 + lane) * 8);
            }
            #pragma unroll
            for (int s = 0; s < 3; ++s)
                #pragma unroll
                for (int ks = 0; ks < 2; ++ks) {
                    const int coff = r * 4096 + ks * 2048 + s * 16;
                    #pragma unroll
                    for (int t = 0; t < 4; ++t)
                        if (t < ntile) {
                            s8v bf = *(const s8v*)(XB + bofs[t] + coff);
                            acc0[t] = __builtin_amdgcn_mfma_f32_32x32x16_bf16(a0[s * 2 + ks], bf, acc0[t], 0, 0, 0);
                            acc1[t] = __builtin_amdgcn_mfma_f32_32x32x16_bf16(a1[s * 2 + ks], bf, acc1[t], 0, 0, 0);
                        }
                }
        }
        __syncthreads();
    }

    #pragma unroll
    for (int t = 0; t < 4; ++t)
        if (t < ntile) {
            int p = (noff + t) * 32 + n, pr = p / 56, pc = p - pr * 56;
            float* op = out + (size_t)b * 256 * NHW + (size_t)(r0 + pr) * 56 + pc;
            #pragma unroll
            for (int reg = 0; reg < 16; ++reg) {
                int m = (reg & 3) + 8 * (reg >> 2) + 4 * hf;
                int o0 = oq * 64 + m;
                op[(size_t)o0 * NHW] = acc0[t][reg] + bias[kb * NOC + o0];
                op[(size_t)(o0 + 32) * NHW] = acc1[t][reg] + bias[kb * NOC + o0 + 32];
            }
        }
}

// ---------------- fallback fp32 path ----------------

__global__ __launch_bounds__(256) void k_pool(const float* __restrict__ x,
                                              float* __restrict__ ws) {
    int plane = blockIdx.x;
    const float* p = x + (size_t)plane * NHW;
    float s = 0.f;
    for (int i = threadIdx.x; i < NHW; i += 256) s += p[i];
    for (int off = 32; off > 0; off >>= 1) s += __shfl_down(s, off, 64);
    __shared__ float part[4];
    int lane = threadIdx.x & 63, wv = threadIdx.x >> 6;
    if (lane == 0) part[wv] = s;
    __syncthreads();
    if (threadIdx.x == 0)
        ws[WS_POOLED + plane] = part[0] + part[1] + part[2] + part[3];
}

__global__ __launch_bounds__(256) void k_fc(const float* __restrict__ w_fc1,
                                            const float* __restrict__ w_fc2,
                                            const float* __restrict__ b_fc2,
                                            float* __restrict__ ws,
                                            float* __restrict__ out_raw) {
    __shared__ float pl[NB * NC];
    __shared__ float hs[NB][NHID];
    __shared__ float raws[NB][NK];
    for (int i = threadIdx.x; i < NB * NC; i += 256)
        pl[i] = ws[WS_POOLED + i] * (1.0f / NHW);
    __syncthreads();
    for (int idx = threadIdx.x; idx < NB * NHID; idx += 256) {
        int b = idx / NHID, j = idx % NHID;
        float s = 0.f;
        for (int c = 0; c < NC; ++c) s = fmaf(pl[b * NC + c], w_fc1[j * NC + c], s);
        hs[b][j] = fmaxf(s, 0.f);
    }
    __syncthreads();
    if (threadIdx.x < NB * NK) {
        int b = threadIdx.x / NK, k = threadIdx.x % NK;
        float s = b_fc2[k];
        for (int j = 0; j < NHID; ++j) s = fmaf(hs[b][j], w_fc2[k * NHID + j], s);
        raws[b][k] = s;
        out_raw[b * NK + k] = s;
    }
    __syncthreads();
    if (threadIdx.x < NB) {
        int best = 0;
        for (int k = 1; k < NK; ++k)
            if (raws[threadIdx.x][k] > raws[threadIdx.x][best]) best = k;
        ((int*)(ws + WS_KB))[threadIdx.x] = best;
    }
}

__global__ __launch_bounds__(256) void k_maxtanh(const float* __restrict__ w,
                                                 float* __restrict__ ws) {
    float m = 0.f;
    for (int i = blockIdx.x * 256 + threadIdx.x; i < WN; i += gridDim.x * 256)
        m = fmaxf(m, fabsf(tanhf(w[i])));
    for (int off = 32; off > 0; off >>= 1) m = fmaxf(m, __shfl_down(m, off, 64));
    __shared__ float part[4];
    int lane = threadIdx.x & 63, wv = threadIdx.x >> 6;
    if (lane == 0) part[wv] = m;
    __syncthreads();
    if (threadIdx.x == 0) {
        float t = fmaxf(fmaxf(part[0], part[1]), fmaxf(part[2], part[3]));
        atomicMax((unsigned int*)ws + WS_MAX, __float_as_uint(t));
    }
}

__global__ __launch_bounds__(256) void k_quant(const float* __restrict__ w,
                                               float* __restrict__ ws) {
    float maxt = __uint_as_float(((const unsigned int*)ws)[WS_MAX]);
    float* wqf = ws + WS_WQF;
    for (int i = blockIdx.x * 256 + threadIdx.x; i < WN; i += gridDim.x * 256) {
        float t = tanhf(w[i]);
        float xq = (t / maxt + 1.0f) * 0.5f;
        #pragma unroll
        for (int k = 0; k < NK; ++k) {
            float a = (float)(4 << k);
            float q = fminf(floorf(a * xq), a - 1.0f) / a;
            wqf[(size_t)k * WN + i] = q * 2.0f - 1.0f;
        }
    }
}

__global__ __launch_bounds__(256) void k_conv(const float* __restrict__ x,
                                              const float* __restrict__ bias,
                                              const float* __restrict__ ws,
                                              float* __restrict__ out) {
    const int o_base = blockIdx.x * 16;
    const int row_base = blockIdx.y * 7;
    const int b = blockIdx.z;
    const int tid = threadIdx.x;
    const int w = tid & 63;
    const int og = tid >> 6;
    const int wc = (w < 56) ? w : 55;
    const int kb = ((const int*)(ws + WS_KB))[b];
    const float* wqf = ws + WS_WQF + (size_t)kb * WN;

    __shared__ float Xl[8][9][58];
    __shared__ float Wl[16][72];

    float acc[4][7];
    #pragma unroll
    for (int i = 0; i < 4; ++i)
        #pragma unroll
        for (int j = 0; j < 7; ++j) acc[i][j] = 0.f;

    for (int c0 = 0; c0 < NC; c0 += 8) {
        for (int idx = tid; idx < 1152; idx += 256) {
            int o = idx / 72, rem = idx - o * 72;
            Wl[o][rem] = wqf[(size_t)(o_base + o) * 2304 + c0 * 9 + rem];
        }
        for (int idx = tid; idx < 4176; idx += 256) {
            int c = idx / 522, rem = idx - c * 522;
            int ly = rem / 58, lx = rem - ly * 58;
            int gy = row_base - 1 + ly, gx = lx - 1;
            float v = 0.f;
            if (gy >= 0 && gy < NH && (unsigned)gx < (unsigned)NW)
                v = x[(((size_t)b * NC + c0 + c) * NH + gy) * NW + gx];
            Xl[c][ly][lx] = v;
        }
        __syncthreads();
        #pragma unroll 1
        for (int c = 0; c < 8; ++c) {
            float xv[9][3];
            #pragma unroll
            for (int ly = 0; ly < 9; ++ly)
                #pragma unroll
                for (int s = 0; s < 3; ++s)
                    xv[ly][s] = Xl[c][ly][wc + s];
            float wvv[4][9];
            #pragma unroll
            for (int i = 0; i < 4; ++i)
                #pragma unroll
                for (int t = 0; t < 9; ++t)
                    wvv[i][t] = Wl[og * 4 + i][c * 9 + t];
            #pragma unroll
            for (int i = 0; i < 4; ++i)
                #pragma unroll
                for (int j = 0; j < 7; ++j)
                    #pragma unroll
                    for (int r = 0; r < 3; ++r)
                        #pragma unroll
                        for (int s = 0; s < 3; ++s)
                            acc[i][j] = fmaf(wvv[i][r * 3 + s], xv[j + r][s], acc[i][j]);
        }
        __syncthreads();
    }

    if (w < 56) {
        #pragma unroll
        for (int i = 0; i < 4; ++i) {
            int o = o_base + og * 4 + i;
            float bb = bias[kb * NOC + o];
            #pragma unroll
            for (int j = 0; j < 7; ++j)
                out[(((size_t)b * NOC + o) * NH + (row_base + j)) * NW + w] = acc[i][j] + bb;
        }
    }
}

extern "C" void kernel_launch(void* const* d_in, const int* in_sizes, int n_in,
                              void* d_out, int out_size, void* d_ws, size_t ws_size,
                              hipStream_t stream) {
    const float* x      = (const float*)d_in[0];
    const float* w_fc1  = (const float*)d_in[1];
    const float* w_fc2  = (const float*)d_in[2];
    const float* b_fc2  = (const float*)d_in[3];
    const float* weight = (const float*)d_in[4];
    const float* bias   = (const float*)d_in[5];
    float* out = (float*)d_out;
    float* ws  = (float*)d_ws;

    if (ws_size >= WS_NEED) {
        hipLaunchKernelGGL(k_prep, dim3(1152), dim3(256), 0, stream, x, weight, ws, out);
        hipLaunchKernelGGL(k_mid, dim3(144), dim3(256), 0, stream,
                           w_fc1, w_fc2, b_fc2, weight, ws, out, out + OUT0);
        hipLaunchKernelGGL(k_conv_mfma, dim3(4, 7, 16), dim3(256), 0, stream, bias, ws, out);
    } else {
        hipLaunchKernelGGL(k_pool, dim3(NB * NC), dim3(256), 0, stream, x, ws);
        hipLaunchKernelGGL(k_fc, dim3(1), dim3(256), 0, stream,
                           w_fc1, w_fc2, b_fc2, ws, out + OUT0);
        hipLaunchKernelGGL(k_maxtanh, dim3(256), dim3(256), 0, stream, weight, ws);
        hipLaunchKernelGGL(k_quant, dim3(512), dim3(256), 0, stream, weight, ws);
        hipLaunchKernelGGL(k_conv, dim3(16, 8, NB), dim3(256), 0, stream, x, bias, ws, out);
    }
}